// Round 6
// baseline (180.212 us; speedup 1.0000x reference)
//
#include <hip/hip_runtime.h>

#define NN 100000
#define EE 1600000
#define DIN 128
#define DOUT 64
#define NH 4

typedef __attribute__((ext_vector_type(8))) short bf16x8;
typedef __attribute__((ext_vector_type(8))) unsigned short u16x8;
typedef __attribute__((ext_vector_type(4))) float f32x4;

__device__ __forceinline__ float elu_f(float x) {
  return x > 0.f ? x : (__expf(x) - 1.f);
}
__device__ __forceinline__ float b2f(unsigned short u) {
  union { unsigned int i; float f; } v; v.i = ((unsigned int)u) << 16; return v.f;
}
__device__ __forceinline__ unsigned short f2b(float f) {
  union { float f; unsigned int i; } v; v.f = f;
  unsigned int r = v.i + 0x7fffu + ((v.i >> 16) & 1u);
  return (unsigned short)(r >> 16);
}

// Kernel 0: W [H][DIN][DOUT] fp32 -> WbfT [H*DOUT][DIN] bf16 (64 KB, L2-hot).
__global__ __launch_bounds__(256) void wbf_k(
    const float* __restrict__ W, unsigned short* __restrict__ wbt) {
  int idx = blockIdx.x * 256 + threadIdx.x;  // 32768 total
  int col = idx >> 7, k = idx & 127;         // col = h*64+j
  int h = col >> 6, j = col & 63;
  wbt[idx] = f2b(W[(size_t)h * DIN * DOUT + k * DOUT + j]);
}

// Kernel 1: CSR row_ptr from sorted edge_row via binary search.
__global__ __launch_bounds__(256) void build_row_ptr_k(
    const int* __restrict__ erow, int* __restrict__ rp) {
  int r = blockIdx.x * 256 + threadIdx.x;
  if (r > NN) return;
  int lo = 0, hi = EE;
  while (lo < hi) {
    int mid = (lo + hi) >> 1;
    if (erow[mid] < r) lo = mid + 1; else hi = mid;
  }
  rp[r] = lo;
}

// Kernel 2 (MFMA): block = 64 rows x 256 cols, 4 waves = 4 heads.
// A staged once into LDS as bf16 (XOR-swizzled), shared by the 4 waves.
// MFMA operands SWAPPED (W as 'a', input as 'b') -> D = xh^T fragment.
__global__ __launch_bounds__(256) void proj_mfma_k(
    const float* __restrict__ inp, const unsigned short* __restrict__ wbt,
    const float* __restrict__ a1, const float* __restrict__ a2,
    float* __restrict__ f1p, float* __restrict__ f2p,
    unsigned short* __restrict__ xh) {
  __shared__ unsigned short lds_a[64 * 128];  // 16 KB bf16 A-tile, swizzled
  const int tid = threadIdx.x;
  const int h = tid >> 6;   // wave = head
  const int l = tid & 63;
  const int lr = l & 15;
  const int lk = l >> 4;
  const int row0 = blockIdx.x * 64;

  // --- stage A: 64 rows x 128 k, fp32 -> bf16, swizzle byte^=(row&7)<<4 ---
  #pragma unroll
  for (int i = 0; i < 8; ++i) {
    const int idx = i * 256 + tid;       // float4 index, 2048 total
    const int row = idx >> 5;            // 0..63
    const int c4 = idx & 31;             // float4 chunk within row
    int grow = row0 + row;
    if (grow >= NN) grow = NN - 1;
    const float4 v = *(const float4*)(inp + (size_t)grow * DIN + c4 * 4);
    ushort4 w;
    w.x = f2b(v.x); w.y = f2b(v.y); w.z = f2b(v.z); w.w = f2b(v.w);
    const int byte_off = row * 256 + ((c4 * 8) ^ ((row & 7) << 4));
    *(ushort4*)((char*)lds_a + byte_off) = w;
  }

  // W fragments while staging is in flight: 'a' operand, col = h*64+n*16+lr
  bf16x8 bf[4][4];
  #pragma unroll
  for (int n = 0; n < 4; ++n) {
    const int col = h * DOUT + n * 16 + lr;
    #pragma unroll
    for (int kc = 0; kc < 4; ++kc)
      bf[n][kc] = *(const bf16x8*)(wbt + (size_t)col * DIN + kc * 32 + lk * 8);
  }
  __syncthreads();

  f32x4 acc[4][4];
  #pragma unroll
  for (int m = 0; m < 4; ++m)
    #pragma unroll
    for (int n = 0; n < 4; ++n)
      acc[m][n] = (f32x4)(0.f);

  #pragma unroll
  for (int m = 0; m < 4; ++m) {
    const int r = m * 16 + lr;
    bf16x8 af[4];
    #pragma unroll
    for (int kc = 0; kc < 4; ++kc)
      af[kc] = *(const bf16x8*)((char*)lds_a + r * 256 +
                                ((kc * 64 + lk * 16) ^ ((r & 7) << 4)));
    #pragma unroll
    for (int kc = 0; kc < 4; ++kc)
      #pragma unroll
      for (int n = 0; n < 4; ++n)
        acc[m][n] = __builtin_amdgcn_mfma_f32_16x16x32_bf16(
            bf[n][kc], af[kc], acc[m][n], 0, 0, 0);
  }

  // epilogue: lane holds xh[row0+m*16+lr][h*64 + n*16 + lk*4 + reg]
  float4 a1q[4], a2q[4];
  #pragma unroll
  for (int n = 0; n < 4; ++n) {
    a1q[n] = *(const float4*)(a1 + h * DOUT + n * 16 + lk * 4);
    a2q[n] = *(const float4*)(a2 + h * DOUT + n * 16 + lk * 4);
  }
  #pragma unroll
  for (int m = 0; m < 4; ++m) {
    const int row = row0 + m * 16 + lr;
    const bool ok = row < NN;
    float p1 = 0.f, p2 = 0.f;
    #pragma unroll
    for (int n = 0; n < 4; ++n) {
      const f32x4 a = acc[m][n];
      ushort4 pk;
      pk.x = f2b(a[0]); pk.y = f2b(a[1]); pk.z = f2b(a[2]); pk.w = f2b(a[3]);
      if (ok)
        *(ushort4*)(xh + (size_t)row * (NH * DOUT) + h * DOUT + n * 16 + lk * 4) = pk;
      p1 = fmaf(a[0], a1q[n].x, p1); p1 = fmaf(a[1], a1q[n].y, p1);
      p1 = fmaf(a[2], a1q[n].z, p1); p1 = fmaf(a[3], a1q[n].w, p1);
      p2 = fmaf(a[0], a2q[n].x, p2); p2 = fmaf(a[1], a2q[n].y, p2);
      p2 = fmaf(a[2], a2q[n].z, p2); p2 = fmaf(a[3], a2q[n].w, p2);
    }
    p1 += __shfl_xor(p1, 16); p1 += __shfl_xor(p1, 32);
    p2 += __shfl_xor(p2, 16); p2 += __shfl_xor(p2, 32);
    if (ok && lk == 0) {
      f1p[(size_t)row * NH + h] = elu_f(p1);
      f2p[(size_t)row * NH + h] = elu_f(p2);
    }
  }
}

// Kernel 3: one wave per destination row, TWO edges per pass (half-wave each).
// Within a half-wave (32 lanes): head g = local>>3, col chunk c8 = local&7;
// each lane gathers ushort8 (16 B) -> the wave's single gather instruction
// covers both edges' full 512 B xh rows. 8-pair (16-edge) batches.
__global__ __launch_bounds__(256) void agg_k(
    const int* __restrict__ rp, const int* __restrict__ ecol,
    const float* __restrict__ eval, const float* __restrict__ f1p,
    const float* __restrict__ f2p, const unsigned short* __restrict__ xh,
    const float* __restrict__ b, float* __restrict__ out) {
  const int tid = threadIdx.x;
  const int wave = tid >> 6, lane = tid & 63;
  const int r = blockIdx.x * 4 + wave;
  if (r >= NN) return;
  const int half = lane >> 5;     // 0: even-indexed edge of pair, 1: odd
  const int local = lane & 31;
  const int g = local >> 3;       // head
  int rb = __builtin_amdgcn_readfirstlane(rp[r]);
  int re = __builtin_amdgcn_readfirstlane(rp[r + 1]);
  const float f1r = f1p[(size_t)r * NH + g];
  float acc[8];
  #pragma unroll
  for (int j = 0; j < 8; ++j) acc[j] = 0.f;
  float ssum = 0.f;
  int e = rb;
  for (; e + 16 <= re; e += 16) {
    int cc[8]; float vv[8];
    #pragma unroll
    for (int p = 0; p < 8; ++p) {
      const int ee = e + 2 * p + half;
      cc[p] = ecol[ee]; vv[p] = eval[ee];
    }
    u16x8 xv[8]; float f2v[8];
    #pragma unroll
    for (int p = 0; p < 8; ++p) {
      xv[p] = *(const u16x8*)(xh + (size_t)cc[p] * (NH * DOUT) + local * 8);
      f2v[p] = f2p[(size_t)cc[p] * NH + g];
    }
    #pragma unroll
    for (int p = 0; p < 8; ++p) {
      const float t = vv[p] * (f1r + f2v[p]);
      const float ex = __expf(fmaxf(t, 0.2f * t));
      ssum += ex;
      #pragma unroll
      for (int j = 0; j < 8; ++j)
        acc[j] = fmaf(ex, b2f((unsigned short)xv[p][j]), acc[j]);
    }
  }
  if (e < re) {  // masked batch: up to 15 remaining edges
    int cc[8]; float vv[8]; bool ok[8];
    #pragma unroll
    for (int p = 0; p < 8; ++p) {
      int ee = e + 2 * p + half;
      ok[p] = ee < re;
      if (!ok[p]) ee = re - 1;
      cc[p] = ecol[ee]; vv[p] = eval[ee];
    }
    u16x8 xv[8]; float f2v[8];
    #pragma unroll
    for (int p = 0; p < 8; ++p) {
      xv[p] = *(const u16x8*)(xh + (size_t)cc[p] * (NH * DOUT) + local * 8);
      f2v[p] = f2p[(size_t)cc[p] * NH + g];
    }
    #pragma unroll
    for (int p = 0; p < 8; ++p) {
      const float t = vv[p] * (f1r + f2v[p]);
      float ex = __expf(fmaxf(t, 0.2f * t));
      ex = ok[p] ? ex : 0.f;
      ssum += ex;
      #pragma unroll
      for (int j = 0; j < 8; ++j)
        acc[j] = fmaf(ex, b2f((unsigned short)xv[p][j]), acc[j]);
    }
  }
  // merge the two half-waves (disjoint edge subsets of the same row)
  ssum += __shfl_xor(ssum, 32);
  #pragma unroll
  for (int j = 0; j < 8; ++j) acc[j] += __shfl_xor(acc[j], 32);
  const float inv = (re > rb) ? (1.f / ssum) : 0.f;
  float o[8];
  #pragma unroll
  for (int j = 0; j < 8; ++j) {
    o[j] = elu_f(acc[j] * inv + b[local * 8 + j]);
    // mean over heads: lanes {c8, c8+8, c8+16, c8+24} hold same col, diff head
    o[j] += __shfl_xor(o[j], 8);
    o[j] += __shfl_xor(o[j], 16);
    o[j] *= 0.25f;
  }
  if (lane < 8) {
    f32x4 o0 = {o[0], o[1], o[2], o[3]};
    f32x4 o1 = {o[4], o[5], o[6], o[7]};
    f32x4* dst = (f32x4*)(out + (size_t)r * DOUT + local * 8);
    __builtin_nontemporal_store(o0, dst);
    __builtin_nontemporal_store(o1, dst + 1);
  }
}

extern "C" void kernel_launch(void* const* d_in, const int* in_sizes, int n_in,
                              void* d_out, int out_size, void* d_ws, size_t ws_size,
                              hipStream_t stream) {
  const float* inp = (const float*)d_in[0];
  const float* W   = (const float*)d_in[1];
  const float* a1  = (const float*)d_in[2];
  const float* a2  = (const float*)d_in[3];
  const float* b   = (const float*)d_in[4];
  const float* ev  = (const float*)d_in[5];
  const int* erow  = (const int*)d_in[6];
  const int* ecol  = (const int*)d_in[7];
  float* out = (float*)d_out;

  char* ws = (char*)d_ws;
  size_t off = 0;
  int* rp = (int*)(ws + off);
  off += (((size_t)(NN + 1) * 4) + 255) & ~(size_t)255;
  float* f1p = (float*)(ws + off);
  off += (((size_t)NH * NN * 4) + 255) & ~(size_t)255;
  float* f2p = (float*)(ws + off);
  off += (((size_t)NH * NN * 4) + 255) & ~(size_t)255;
  unsigned short* xh = (unsigned short*)(ws + off);
  off += (((size_t)NN * NH * DOUT * 2) + 255) & ~(size_t)255;
  unsigned short* wbt = (unsigned short*)(ws + off);

  wbf_k<<<(NH * DIN * DOUT) / 256, 256, 0, stream>>>(W, wbt);
  build_row_ptr_k<<<(NN + 1 + 255) / 256, 256, 0, stream>>>(erow, rp);
  proj_mfma_k<<<(NN + 63) / 64, 256, 0, stream>>>(inp, wbt, a1, a2, f1p, f2p, xh);
  agg_k<<<(NN + 3) / 4, 256, 0, stream>>>(rp, ecol, ev, f1p, f2p, xh, b, out);
}